// Round 1
// baseline (19002.727 us; speedup 1.0000x reference)
//
#include <hip/hip_runtime.h>
#include <hip/hip_fp16.h>
#include <stdint.h>

// ---------------------------------------------------------------------------
// SequentialEMGPoseLSTM: 2-layer LSTM (H=256, B=64, T=4096) + LeakyReLU+Linear
//
// Strategy: persistent-weight recurrent blocks (one CU per batch chain), fp16
// Whh split VGPR(6/8 rows)+LDS(2/8 rows), v_dot2_f32_f16 inner product,
// fp32 cell state. Layer pipeline via chunked launches:
//   launch L: [role0: layer0 chunk L] [roleG: xw1 GEMM chunk L-1 (f16 MFMA)]
//             [role1: layer1+head chunk L-2]
// Stream ordering provides all inter-role dependencies (no device sync).
// ---------------------------------------------------------------------------

#define T_SEQ 4096
#define NB    64
#define HID   256
#define G4    1024
#define INCH  16
#define OC    20

typedef _Float16 h2v   __attribute__((ext_vector_type(2)));
typedef _Float16 f16x8 __attribute__((ext_vector_type(8)));
typedef float    f32x4 __attribute__((ext_vector_type(4)));

__device__ __forceinline__ float fdot2(uint32_t a, uint32_t b, float c) {
  return __builtin_amdgcn_fdot2(__builtin_bit_cast(h2v, a),
                                __builtin_bit_cast(h2v, b), c, false);
}
__device__ __forceinline__ float sigf(float x) {
  x = fminf(fmaxf(x, -30.f), 30.f);
  return 1.f / (1.f + __expf(-x));
}
__device__ __forceinline__ float tanhf_fast(float x) {
  x = fminf(fmaxf(x, -15.f), 15.f);
  float e = __expf(-2.f * x);
  return (1.f - e) / (1.f + e);
}

struct SmemR {
  __half w[256 * 256];   // Whh rows 768..1023 (o-gate), [row][k], 128 KB
  uint32_t hbuf[128];    // h as packed f16x2 (256 halves)
  float gates[1024];
  float bsum[1024];
  union {
    uint32_t xb[512 * 8];            // layer0: packed x pairs [tt][dp], Tc<=512
    struct {
      uint32_t abuf[128];            // layer1: leaky(h2) packed f16x2
      __half   whd[20 * 264];        // head weights, padded rows
      float    bh[20];
    } h1;
  } u;
};
struct SmemG {
  __half a[128 * 40];    // h1 tile [tb][k] (+pad)
  __half b[64 * 40];     // Wih1 tile [g][k] (+pad)
};
union Smem { SmemR r; SmemG g; };

struct Params {
  const float* x;
  const __half *wh0, *wh1, *wi0, *wi1, *whd;
  const float  *bs0, *bs1, *bhd;
  float *h0s, *c0s, *h1s, *c1s;
  __half* h1w; const __half* h1r;
  float* xww;  const float* xwr;
  float* y;
  int L, Tc, nch;
};

// ---------------------------------------------------------------------------
// Recurrent role: one block == one batch chain. 512 threads.
// slice = tid&3 covers k in [64*slice, 64*slice+64); rg = tid>>2 (0..127).
// Thread handles gate rows r = rg + 128*j, j=0..7 (j<6 reg weights, j>=6 LDS).
// ---------------------------------------------------------------------------
template <int LAYER>
__device__ void role_rec(SmemR& S, int ch, const Params& P, int b) {
  if (ch < 0 || ch >= P.nch) return;
  const int tid   = threadIdx.x;
  const int slice = tid & 3;
  const int rg    = tid >> 2;
  const int Tc    = P.Tc;
  const __half* whh = (LAYER == 0) ? P.wh0 : P.wh1;

  // Stage LDS-resident weight rows 768..1023 (131072 B = 8192 uint4).
  {
    const uint4* src = (const uint4*)(whh + 768 * 256);
    uint4* dst = (uint4*)S.w;
    for (int i = tid; i < 8192; i += 512) dst[i] = src[i];
  }
  // Stage bias.
  {
    const float* bs = (LAYER == 0) ? P.bs0 : P.bs1;
    for (int i = tid; i < 1024; i += 512) S.bsum[i] = bs[i];
  }
  const int t0 = ch * Tc;
  if (LAYER == 0) {
    // Stage x chunk as packed f16 pairs: xb[tt*8+dp] = (x[2dp], x[2dp+1]) at t0+tt.
    for (int i = tid; i < Tc * 8; i += 512) {
      int dp = i / Tc, tt = i - dp * Tc;
      float v0 = P.x[(b * INCH + 2 * dp) * T_SEQ + t0 + tt];
      float v1 = P.x[(b * INCH + 2 * dp + 1) * T_SEQ + t0 + tt];
      uint32_t pv = (uint32_t)__half_as_ushort(__float2half(v0)) |
                    ((uint32_t)__half_as_ushort(__float2half(v1)) << 16);
      S.u.xb[tt * 8 + dp] = pv;
    }
  } else {
    for (int i = tid; i < OC * 256; i += 512) {
      int o = i >> 8, k = i & 255;
      S.u.h1.whd[o * 264 + k] = P.whd[i];
    }
    if (tid < OC) S.u.h1.bh[tid] = P.bhd[tid];
  }

  // Register-resident weights: rows j=0..5, 64 halves each (32 packed u32).
  uint32_t wr[6][32];
#pragma unroll
  for (int j = 0; j < 6; j++) {
    const uint4* p = (const uint4*)(whh + (rg + 128 * j) * 256 + slice * 64);
#pragma unroll
    for (int q = 0; q < 8; q++) {
      uint4 v = p[q];
      wr[j][4 * q] = v.x; wr[j][4 * q + 1] = v.y;
      wr[j][4 * q + 2] = v.z; wr[j][4 * q + 3] = v.w;
    }
  }
  // Layer0 input weights: 4 input dims per slice (2 packed u32 per row).
  uint32_t wx[8][2];
  if (LAYER == 0) {
#pragma unroll
    for (int j = 0; j < 8; j++) {
      const uint32_t* p = (const uint32_t*)(P.wi0 + (rg + 128 * j) * INCH + slice * 4);
      wx[j][0] = p[0]; wx[j][1] = p[1];
    }
  }

  // Load / init state. c,h live in fp32 registers of threads 0..255.
  float* hs = (LAYER == 0) ? P.h0s : P.h1s;
  float* cs = (LAYER == 0) ? P.c0s : P.c1s;
  float hval = 0.f, cval = 0.f;
  if (tid < 256) {
    if (ch != 0) { hval = hs[b * 256 + tid]; cval = cs[b * 256 + tid]; }
    ((__half*)S.hbuf)[tid] = __float2half(hval);
  }

  // Layer1: prefetch xw row for tt=0 (writer lanes only).
  float xwpre[8];
  if (LAYER == 1 && slice == 0) {
#pragma unroll
    for (int j = 0; j < 8; j++)
      xwpre[j] = P.xwr[(0 * NB + b) * G4 + rg + 128 * j];
  }
  __syncthreads();

  for (int tt = 0; tt < Tc; ++tt) {
    float acc[8];
#pragma unroll
    for (int j = 0; j < 8; j++) acc[j] = 0.f;

    // Phase 1: gate dot products over k-slice (staged in two halves of h).
#pragma unroll
    for (int hf = 0; hf < 2; ++hf) {
      uint32_t hh[16];
      const uint4* hp = (const uint4*)&S.hbuf[slice * 32 + hf * 16];
#pragma unroll
      for (int q = 0; q < 4; q++) {
        uint4 v = hp[q];
        hh[4 * q] = v.x; hh[4 * q + 1] = v.y; hh[4 * q + 2] = v.z; hh[4 * q + 3] = v.w;
      }
#pragma unroll
      for (int j = 0; j < 6; j++) {
        float a = acc[j];
#pragma unroll
        for (int q = 0; q < 16; q++) a = fdot2(wr[j][hf * 16 + q], hh[q], a);
        acc[j] = a;
      }
#pragma unroll
      for (int j = 6; j < 8; j++) {
        const uint4* wp =
            (const uint4*)&S.w[((j - 6) * 128 + rg) * 256 + slice * 64 + hf * 32];
        float a = acc[j];
#pragma unroll
        for (int q = 0; q < 4; q++) {
          uint4 v = wp[q];
          a = fdot2(v.x, hh[4 * q], a);
          a = fdot2(v.y, hh[4 * q + 1], a);
          a = fdot2(v.z, hh[4 * q + 2], a);
          a = fdot2(v.w, hh[4 * q + 3], a);
        }
        acc[j] = a;
      }
    }
    if (LAYER == 0) {
      uint32_t xv0 = S.u.xb[tt * 8 + 2 * slice];
      uint32_t xv1 = S.u.xb[tt * 8 + 2 * slice + 1];
#pragma unroll
      for (int j = 0; j < 8; j++) {
        acc[j] = fdot2(wx[j][0], xv0, acc[j]);
        acc[j] = fdot2(wx[j][1], xv1, acc[j]);
      }
    }
    // Reduce over 4 k-slices (lanes differing in bits 0..1).
#pragma unroll
    for (int j = 0; j < 8; j++) {
      acc[j] += __shfl_xor(acc[j], 1);
      acc[j] += __shfl_xor(acc[j], 2);
    }
    if (slice == 0) {
#pragma unroll
      for (int j = 0; j < 8; j++) {
        int r = rg + 128 * j;
        float g = acc[j] + S.bsum[r];
        if (LAYER == 1) g += xwpre[j];
        S.gates[r] = g;
      }
    }
    // Prefetch next step's xw while gates settle.
    if (LAYER == 1 && slice == 0 && tt + 1 < Tc) {
#pragma unroll
      for (int j = 0; j < 8; j++)
        xwpre[j] = P.xwr[((tt + 1) * NB + b) * G4 + rg + 128 * j];
    }
    __syncthreads();

    // Phase 2: state update (thread ch<256 owns channel ch).
    if (tid < 256) {
      float gi = S.gates[tid];
      float gf = S.gates[256 + tid];
      float gg = S.gates[512 + tid];
      float go = S.gates[768 + tid];
      float iv = sigf(gi), fv = sigf(gf), gv = tanhf_fast(gg), ov = sigf(go);
      cval = fv * cval + iv * gv;
      hval = ov * tanhf_fast(cval);
      __half h16 = __float2half(hval);
      ((__half*)S.hbuf)[tid] = h16;
      if (LAYER == 0) {
        P.h1w[(tt * NB + b) * 256 + tid] = h16;
      } else {
        float a = hval > 0.f ? hval : 0.01f * hval;
        ((__half*)S.u.h1.abuf)[tid] = __float2half(a);
      }
    }
    __syncthreads();

    // Phase 3 (layer1): head. 20 outputs x 8 lanes x 32 k each.
    if (LAYER == 1) {
      if (tid < OC * 8) {
        int o = tid >> 3, ks = tid & 7;
        const uint4* wp = (const uint4*)&S.u.h1.whd[o * 264 + ks * 32];
        const uint4* ap = (const uint4*)((const __half*)S.u.h1.abuf + ks * 32);
        float a = 0.f;
#pragma unroll
        for (int q = 0; q < 4; q++) {
          uint4 w4 = wp[q];
          uint4 a4 = ap[q];
          a = fdot2(w4.x, a4.x, a);
          a = fdot2(w4.y, a4.y, a);
          a = fdot2(w4.z, a4.z, a);
          a = fdot2(w4.w, a4.w, a);
        }
        a += __shfl_xor(a, 1);
        a += __shfl_xor(a, 2);
        a += __shfl_xor(a, 4);
        if (ks == 0) P.y[(b * OC + o) * T_SEQ + t0 + tt] = a + S.u.h1.bh[o];
      }
      // No extra barrier needed: abuf is only rewritten after next step's
      // phase-1 barrier, which every thread reaches after finishing here.
    }
  }
  if (tid < 256) {
    hs[b * 256 + tid] = hval;
    cs[b * 256 + tid] = cval;
  }
}

// ---------------------------------------------------------------------------
// GEMM role: xw1[tb, g] = sum_k h1[tb,k] * Wih1[g,k], f16 MFMA, fp32 out.
// Block tile 128(tb) x 64(g); 8 waves as 4(M) x 2(N), each 32x32 (2x2 frags).
// ---------------------------------------------------------------------------
__device__ void role_gemm(SmemG& S, int chG, const Params& P) {
  if (chG < 0 || chG >= P.nch) return;
  const int bid = blockIdx.x - 128;
  const int nt = bid & 15, mt = bid >> 4;
  const int tb0 = mt * 128, g0 = nt * 64;
  const int tid = threadIdx.x, lane = tid & 63, w = tid >> 6;
  const int wm = w & 3, wn = w >> 2;

  f32x4 cacc[2][2] = {};
  for (int kk = 0; kk < 256; kk += 32) {
    __syncthreads();
    {
      int row = tid >> 2, q = tid & 3;
      const uint4* src = (const uint4*)(P.h1r + (tb0 + row) * 256 + kk + q * 8);
      *(uint4*)&S.a[row * 40 + q * 8] = *src;
    }
    if (tid < 256) {
      int row = tid >> 2, q = tid & 3;
      const uint4* src = (const uint4*)(P.wi1 + (g0 + row) * 256 + kk + q * 8);
      *(uint4*)&S.b[row * 40 + q * 8] = *src;
    }
    __syncthreads();
    f16x8 af[2], bf[2];
#pragma unroll
    for (int mi = 0; mi < 2; mi++)
      af[mi] = *(const f16x8*)&S.a[(wm * 32 + mi * 16 + (lane & 15)) * 40 + (lane >> 4) * 8];
#pragma unroll
    for (int ni = 0; ni < 2; ni++)
      bf[ni] = *(const f16x8*)&S.b[(wn * 32 + ni * 16 + (lane & 15)) * 40 + (lane >> 4) * 8];
#pragma unroll
    for (int mi = 0; mi < 2; mi++)
#pragma unroll
      for (int ni = 0; ni < 2; ni++)
        cacc[mi][ni] = __builtin_amdgcn_mfma_f32_16x16x32_f16(af[mi], bf[ni], cacc[mi][ni], 0, 0, 0);
  }
#pragma unroll
  for (int mi = 0; mi < 2; mi++)
#pragma unroll
    for (int ni = 0; ni < 2; ni++) {
      int m = wm * 32 + mi * 16 + (lane >> 4) * 4;
      int n = g0 + wn * 32 + ni * 16 + (lane & 15);
#pragma unroll
      for (int r = 0; r < 4; r++)
        P.xww[(size_t)(tb0 + m + r) * G4 + n] = cacc[mi][ni][r];
    }
}

__global__ __launch_bounds__(512, 2) void fused_kernel(Params P) {
  __shared__ Smem S;
  int bid = blockIdx.x;
  if (bid < 64)        role_rec<0>(S.r, P.L, P, bid);
  else if (bid < 128)  role_rec<1>(S.r, P.L - 2, P, bid - 64);
  else                 role_gemm(S.g, P.L - 1, P);
}

// ---------------------------------------------------------------------------
// Prep: cast weights to fp16 into workspace, combine biases.
// ---------------------------------------------------------------------------
__global__ void prep_kernel(const float* Wih0, const float* Whh0,
                            const float* bih0, const float* bhh0,
                            const float* Wih1, const float* Whh1,
                            const float* bih1, const float* bhh1,
                            const float* Whead, const float* bhead,
                            __half* wh0, __half* wh1, __half* wi1, __half* wi0,
                            __half* whd, float* bs0, float* bs1, float* bhd) {
  int i = blockIdx.x * blockDim.x + threadIdx.x;
  if (i < G4 * HID) {
    wh0[i] = __float2half(Whh0[i]);
    wh1[i] = __float2half(Whh1[i]);
    wi1[i] = __float2half(Wih1[i]);
  }
  if (i < G4 * INCH) wi0[i] = __float2half(Wih0[i]);
  if (i < OC * HID)  whd[i] = __float2half(Whead[i]);
  if (i < G4) { bs0[i] = bih0[i] + bhh0[i]; bs1[i] = bih1[i] + bhh1[i]; }
  if (i < OC) bhd[i] = bhead[i];
}

// ---------------------------------------------------------------------------
extern "C" void kernel_launch(void* const* d_in, const int* in_sizes, int n_in,
                              void* d_out, int out_size, void* d_ws, size_t ws_size,
                              hipStream_t stream) {
  const float* x     = (const float*)d_in[0];
  const float* Wih0  = (const float*)d_in[1];
  const float* Whh0  = (const float*)d_in[2];
  const float* bih0  = (const float*)d_in[3];
  const float* bhh0  = (const float*)d_in[4];
  const float* Wih1  = (const float*)d_in[5];
  const float* Whh1  = (const float*)d_in[6];
  const float* bih1  = (const float*)d_in[7];
  const float* bhh1  = (const float*)d_in[8];
  const float* Whead = (const float*)d_in[9];
  const float* bhead = (const float*)d_in[10];
  float* y = (float*)d_out;

  char* ws = (char*)d_ws;
  size_t cur = 0;
  auto alloc = [&](size_t sz) -> char* {
    char* p = ws + cur;
    cur = (cur + sz + 255) & ~(size_t)255;
    return p;
  };
  __half* wh0 = (__half*)alloc(G4 * HID * 2);
  __half* wh1 = (__half*)alloc(G4 * HID * 2);
  __half* wi1 = (__half*)alloc(G4 * HID * 2);
  __half* wi0 = (__half*)alloc(G4 * INCH * 2);
  __half* whd = (__half*)alloc(OC * HID * 2);
  float* bs0 = (float*)alloc(G4 * 4);
  float* bs1 = (float*)alloc(G4 * 4);
  float* bhd = (float*)alloc(OC * 4);
  float* h0s = (float*)alloc(NB * HID * 4);
  float* c0s = (float*)alloc(NB * HID * 4);
  float* h1s = (float*)alloc(NB * HID * 4);
  float* c1s = (float*)alloc(NB * HID * 4);
  size_t fixed = cur;

  int Tc = 512;
  while (Tc > 64) {
    size_t need = fixed + 2 * ((size_t)Tc * NB * HID * 2 + 512) +
                  2 * ((size_t)Tc * NB * G4 * 4 + 512);
    if (need <= ws_size) break;
    Tc >>= 1;
  }
  __half* h1buf[2];
  float* xwbuf[2];
  h1buf[0] = (__half*)alloc((size_t)Tc * NB * HID * 2);
  h1buf[1] = (__half*)alloc((size_t)Tc * NB * HID * 2);
  xwbuf[0] = (float*)alloc((size_t)Tc * NB * G4 * 4);
  xwbuf[1] = (float*)alloc((size_t)Tc * NB * G4 * 4);

  const int nch = T_SEQ / Tc;

  prep_kernel<<<(G4 * HID + 255) / 256, 256, 0, stream>>>(
      Wih0, Whh0, bih0, bhh0, Wih1, Whh1, bih1, bhh1, Whead, bhead,
      wh0, wh1, wi1, wi0, whd, bs0, bs1, bhd);

  const int ngemm = Tc * 8;  // (Tc*64/128) M-tiles * 16 N-tiles
  for (int L = 0; L < nch + 2; ++L) {
    Params P;
    P.x = x;
    P.wh0 = wh0; P.wh1 = wh1; P.wi0 = wi0; P.wi1 = wi1; P.whd = whd;
    P.bs0 = bs0; P.bs1 = bs1; P.bhd = bhd;
    P.h0s = h0s; P.c0s = c0s; P.h1s = h1s; P.c1s = c1s;
    P.h1w = h1buf[L & 1];          // layer0 writes chunk L
    P.h1r = h1buf[(L + 1) & 1];    // gemm reads chunk L-1
    P.xww = xwbuf[(L + 1) & 1];    // gemm writes chunk L-1
    P.xwr = xwbuf[L & 1];          // layer1 reads chunk L-2
    P.y = y;
    P.L = L; P.Tc = Tc; P.nch = nch;
    fused_kernel<<<128 + ngemm, 512, 0, stream>>>(P);
  }
}

// Round 2
// 10868.790 us; speedup vs baseline: 1.7484x; 1.7484x over previous
//
#include <hip/hip_runtime.h>
#include <hip/hip_fp16.h>
#include <stdint.h>

// ---------------------------------------------------------------------------
// SequentialEMGPoseLSTM: 2-layer LSTM (H=256, B=64, T=4096) + LeakyReLU+Linear
//
// R2 changes vs R1 (post-mortem: VGPR_Count=128 -> weights not resident;
// SQ_LDS_BANK_CONFLICT=1.4e8 -> degenerate bank layout):
//  - amdgpu_waves_per_eu(2,2) + asm pins: force 192 weight VGPRs resident.
//  - LDS weight row stride 256->264 halves, hbuf slice 64->72, abuf 32->40:
//    b128 reads now hit the 8-phase minimum (balanced banks).
//  - Single barrier per step: slice-0 lanes own both channels (rg, rg+128)
//    for all 4 gates; gates[] LDS round-trip removed; hbuf/abuf double-buffered.
// ---------------------------------------------------------------------------

#define T_SEQ 4096
#define NB    64
#define HID   256
#define G4    1024
#define INCH  16
#define OC    20

typedef _Float16 h2v   __attribute__((ext_vector_type(2)));
typedef _Float16 f16x8 __attribute__((ext_vector_type(8)));
typedef float    f32x4 __attribute__((ext_vector_type(4)));

__device__ __forceinline__ float fdot2(uint32_t a, uint32_t b, float c) {
  return __builtin_amdgcn_fdot2(__builtin_bit_cast(h2v, a),
                                __builtin_bit_cast(h2v, b), c, false);
}
__device__ __forceinline__ float sigf(float x) {
  x = fminf(fmaxf(x, -30.f), 30.f);
  return 1.f / (1.f + __expf(-x));
}
__device__ __forceinline__ float tanhf_fast(float x) {
  x = fminf(fmaxf(x, -15.f), 15.f);
  float e = __expf(-2.f * x);
  return (1.f - e) / (1.f + e);
}

#define PIN(x) asm volatile("" : "+v"(x))

// Padded LDS layouts (all offsets 16B-aligned):
//  w   : 256 rows x 264 halves (rows 768..1023 of Whh). Row r at bank 4r%32.
//  hbuf: 2 x (4 slices x 72 halves). Slice s at bank offset 4s -> disjoint spans.
//  abuf: 2 x (8 chunks x 40 halves). Chunk ks at bank 20ks%32 -> all distinct.
struct SmemR {
  __half w[256 * 264];        // 135168 B
  uint32_t hbuf[2][144];      // 1152 B
  float bsum[1024];           // 4096 B
  union {
    uint32_t xb[512 * 8];     // layer0: packed x pairs [tt][dp], Tc<=512
    struct {
      __half abuf[2][320];    // layer1: leaky(h2), padded chunks
      __half whd[20 * 264];   // head weights, padded rows
      float  bh[20];
    } h1;
  } u;
};
struct SmemG {
  __half a[128 * 40];
  __half b[64 * 40];
};
union Smem { SmemR r; SmemG g; };

struct Params {
  const float* x;
  const __half *wh0, *wh1, *wi0, *wi1, *whd;
  const float  *bs0, *bs1, *bhd;
  float *h0s, *c0s, *h1s, *c1s;
  __half* h1w; const __half* h1r;
  float* xww;  const float* xwr;
  float* y;
  int L, Tc, nch;
};

// ---------------------------------------------------------------------------
// Recurrent role: one block == one batch chain. 512 threads.
// slice = tid&3 covers k in [64*slice, 64*slice+64); rg = tid>>2 (0..127).
// Thread handles gate rows r = rg + 128*j, j=0..7 (j<6 reg, j>=6 LDS).
// Row rg+128j: j even -> gate (j/2) of channel rg; j odd -> of channel rg+128.
// So slice-0 threads compute the full update of channels rg and rg+128.
// ---------------------------------------------------------------------------
template <int LAYER>
__device__ void role_rec(SmemR& S, int ch, const Params& P, int b) {
  if (ch < 0 || ch >= P.nch) return;
  const int tid   = threadIdx.x;
  const int slice = tid & 3;
  const int rg    = tid >> 2;
  const int Tc    = P.Tc;
  const __half* whh = (LAYER == 0) ? P.wh0 : P.wh1;

  // Stage LDS-resident weight rows 768..1023 into padded layout.
  for (int i = tid; i < 8192; i += 512) {
    int R = i >> 5, oct = i & 31;
    *(uint4*)&S.w[R * 264 + oct * 8] =
        *((const uint4*)(whh + (768 + R) * 256) + oct);
  }
  {
    const float* bs = (LAYER == 0) ? P.bs0 : P.bs1;
    for (int i = tid; i < 1024; i += 512) S.bsum[i] = bs[i];
  }
  const int t0 = ch * Tc;
  if (LAYER == 0) {
    for (int i = tid; i < Tc * 8; i += 512) {
      int dp = i / Tc, tt = i - dp * Tc;
      float v0 = P.x[(b * INCH + 2 * dp) * T_SEQ + t0 + tt];
      float v1 = P.x[(b * INCH + 2 * dp + 1) * T_SEQ + t0 + tt];
      uint32_t pv = (uint32_t)__half_as_ushort(__float2half(v0)) |
                    ((uint32_t)__half_as_ushort(__float2half(v1)) << 16);
      S.u.xb[tt * 8 + dp] = pv;
    }
  } else {
    for (int i = tid; i < OC * 256; i += 512) {
      int o = i >> 8, k = i & 255;
      S.u.h1.whd[o * 264 + k] = P.whd[i];
    }
    if (tid < OC) S.u.h1.bh[tid] = P.bhd[tid];
  }

  // Register-resident weights: rows j=0..5, 64 halves each (32 packed u32).
  uint32_t wr[6][32];
#pragma unroll
  for (int j = 0; j < 6; j++) {
    const uint4* p = (const uint4*)(whh + (rg + 128 * j) * 256 + slice * 64);
#pragma unroll
    for (int q = 0; q < 8; q++) {
      uint4 v = p[q];
      wr[j][4 * q] = v.x; wr[j][4 * q + 1] = v.y;
      wr[j][4 * q + 2] = v.z; wr[j][4 * q + 3] = v.w;
    }
  }
#pragma unroll
  for (int j = 0; j < 6; j++)
#pragma unroll
    for (int q = 0; q < 32; q++) PIN(wr[j][q]);

  uint32_t wx[8][2];
  if (LAYER == 0) {
#pragma unroll
    for (int j = 0; j < 8; j++) {
      const uint32_t* p = (const uint32_t*)(P.wi0 + (rg + 128 * j) * INCH + slice * 4);
      wx[j][0] = p[0]; wx[j][1] = p[1];
    }
#pragma unroll
    for (int j = 0; j < 8; j++) { PIN(wx[j][0]); PIN(wx[j][1]); }
  }

  // State: slice-0 thread owns channels rg and rg+128 (fp32 h,c).
  float* hs = (LAYER == 0) ? P.h0s : P.h1s;
  float* cs = (LAYER == 0) ? P.c0s : P.c1s;
  float hA = 0.f, hB = 0.f, cA = 0.f, cB = 0.f;
  if (slice == 0) {
    if (ch != 0) {
      hA = hs[b * 256 + rg];       cA = cs[b * 256 + rg];
      hB = hs[b * 256 + rg + 128]; cB = cs[b * 256 + rg + 128];
    }
    __half* hb = (__half*)S.hbuf[0];
    hb[(rg >> 6) * 72 + (rg & 63)] = __float2half(hA);
    hb[(2 + (rg >> 6)) * 72 + (rg & 63)] = __float2half(hB);
  }
  float xwpre[8];
  if (LAYER == 1 && slice == 0) {
#pragma unroll
    for (int j = 0; j < 8; j++)
      xwpre[j] = P.xwr[(0 * NB + b) * G4 + rg + 128 * j];
  }
  __syncthreads();

  for (int tt = 0; tt < Tc; ++tt) {
    const __half* hb = (const __half*)S.hbuf[tt & 1];
    float acc[8];
#pragma unroll
    for (int j = 0; j < 8; j++) acc[j] = 0.f;

#pragma unroll
    for (int hf = 0; hf < 2; ++hf) {
      uint32_t hh[16];
      const uint4* hp = (const uint4*)(hb + slice * 72 + hf * 32);
#pragma unroll
      for (int q = 0; q < 4; q++) {
        uint4 v = hp[q];
        hh[4 * q] = v.x; hh[4 * q + 1] = v.y; hh[4 * q + 2] = v.z; hh[4 * q + 3] = v.w;
      }
#pragma unroll
      for (int j = 0; j < 6; j++) {
        float a = acc[j];
#pragma unroll
        for (int q = 0; q < 16; q++) a = fdot2(wr[j][hf * 16 + q], hh[q], a);
        acc[j] = a;
      }
#pragma unroll
      for (int j = 6; j < 8; j++) {
        const uint4* wp =
            (const uint4*)&S.w[((j - 6) * 128 + rg) * 264 + slice * 64 + hf * 32];
        float a = acc[j];
#pragma unroll
        for (int q = 0; q < 4; q++) {
          uint4 v = wp[q];
          a = fdot2(v.x, hh[4 * q], a);
          a = fdot2(v.y, hh[4 * q + 1], a);
          a = fdot2(v.z, hh[4 * q + 2], a);
          a = fdot2(v.w, hh[4 * q + 3], a);
        }
        acc[j] = a;
      }
    }
    if (LAYER == 0) {
      uint32_t xv0 = S.u.xb[tt * 8 + 2 * slice];
      uint32_t xv1 = S.u.xb[tt * 8 + 2 * slice + 1];
#pragma unroll
      for (int j = 0; j < 8; j++) {
        acc[j] = fdot2(wx[j][0], xv0, acc[j]);
        acc[j] = fdot2(wx[j][1], xv1, acc[j]);
      }
    }
#pragma unroll
    for (int j = 0; j < 8; j++) {
      acc[j] += __shfl_xor(acc[j], 1);
      acc[j] += __shfl_xor(acc[j], 2);
    }

    if (slice == 0) {
      float g[8];
#pragma unroll
      for (int j = 0; j < 8; j++) g[j] = acc[j] + S.bsum[rg + 128 * j];
      if (LAYER == 1) {
#pragma unroll
        for (int j = 0; j < 8; j++) g[j] += xwpre[j];
        if (tt + 1 < Tc) {
#pragma unroll
          for (int j = 0; j < 8; j++)
            xwpre[j] = P.xwr[((tt + 1) * NB + b) * G4 + rg + 128 * j];
        }
      }
      float iA = sigf(g[0]), iB = sigf(g[1]);
      float fA = sigf(g[2]), fB = sigf(g[3]);
      float gA = tanhf_fast(g[4]), gB = tanhf_fast(g[5]);
      float oA = sigf(g[6]), oB = sigf(g[7]);
      cA = fA * cA + iA * gA;
      cB = fB * cB + iB * gB;
      hA = oA * tanhf_fast(cA);
      hB = oB * tanhf_fast(cB);
      __half hA16 = __float2half(hA), hB16 = __float2half(hB);
      __half* hw = (__half*)S.hbuf[(tt + 1) & 1];
      hw[(rg >> 6) * 72 + (rg & 63)] = hA16;
      hw[(2 + (rg >> 6)) * 72 + (rg & 63)] = hB16;
      if (LAYER == 0) {
        __half* dst = P.h1w + (size_t)(tt * NB + b) * 256;
        dst[rg] = hA16;
        dst[rg + 128] = hB16;
      } else {
        float aA = hA > 0.f ? hA : 0.01f * hA;
        float aB = hB > 0.f ? hB : 0.01f * hB;
        __half* ab = S.u.h1.abuf[tt & 1];
        ab[(rg >> 5) * 40 + (rg & 31)] = __float2half(aA);
        ab[(4 + (rg >> 5)) * 40 + (rg & 31)] = __float2half(aB);
      }
    }
    __syncthreads();

    // Head (layer1): 20 outputs x 8 lanes x 32 k. Reads abuf[tt&1] written
    // before the barrier; next overwrite of that buffer is 2 steps away and
    // gated by the intervening barrier.
    if (LAYER == 1 && tid < OC * 8) {
      int o = tid >> 3, ks = tid & 7;
      const uint4* wp = (const uint4*)&S.u.h1.whd[o * 264 + ks * 32];
      const uint4* ap = (const uint4*)&S.u.h1.abuf[tt & 1][ks * 40];
      float a = 0.f;
#pragma unroll
      for (int q = 0; q < 4; q++) {
        uint4 w4 = wp[q];
        uint4 a4 = ap[q];
        a = fdot2(w4.x, a4.x, a);
        a = fdot2(w4.y, a4.y, a);
        a = fdot2(w4.z, a4.z, a);
        a = fdot2(w4.w, a4.w, a);
      }
      a += __shfl_xor(a, 1);
      a += __shfl_xor(a, 2);
      a += __shfl_xor(a, 4);
      if (ks == 0) P.y[(b * OC + o) * T_SEQ + t0 + tt] = a + S.u.h1.bh[o];
    }
  }
  if (slice == 0) {
    hs[b * 256 + rg] = hA;        cs[b * 256 + rg] = cA;
    hs[b * 256 + rg + 128] = hB;  cs[b * 256 + rg + 128] = cB;
  }
}

// ---------------------------------------------------------------------------
// GEMM role: xw1[tb, g] = sum_k h1[tb,k] * Wih1[g,k], f16 MFMA, fp32 out.
// ---------------------------------------------------------------------------
__device__ void role_gemm(SmemG& S, int chG, const Params& P) {
  if (chG < 0 || chG >= P.nch) return;
  const int bid = blockIdx.x - 128;
  const int nt = bid & 15, mt = bid >> 4;
  const int tb0 = mt * 128, g0 = nt * 64;
  const int tid = threadIdx.x, lane = tid & 63, w = tid >> 6;
  const int wm = w & 3, wn = w >> 2;

  f32x4 cacc[2][2] = {};
  for (int kk = 0; kk < 256; kk += 32) {
    __syncthreads();
    {
      int row = tid >> 2, q = tid & 3;
      const uint4* src = (const uint4*)(P.h1r + (tb0 + row) * 256 + kk + q * 8);
      *(uint4*)&S.a[row * 40 + q * 8] = *src;
    }
    if (tid < 256) {
      int row = tid >> 2, q = tid & 3;
      const uint4* src = (const uint4*)(P.wi1 + (g0 + row) * 256 + kk + q * 8);
      *(uint4*)&S.b[row * 40 + q * 8] = *src;
    }
    __syncthreads();
    f16x8 af[2], bf[2];
#pragma unroll
    for (int mi = 0; mi < 2; mi++)
      af[mi] = *(const f16x8*)&S.a[(wm * 32 + mi * 16 + (lane & 15)) * 40 + (lane >> 4) * 8];
#pragma unroll
    for (int ni = 0; ni < 2; ni++)
      bf[ni] = *(const f16x8*)&S.b[(wn * 32 + ni * 16 + (lane & 15)) * 40 + (lane >> 4) * 8];
#pragma unroll
    for (int mi = 0; mi < 2; mi++)
#pragma unroll
      for (int ni = 0; ni < 2; ni++)
        cacc[mi][ni] = __builtin_amdgcn_mfma_f32_16x16x32_f16(af[mi], bf[ni], cacc[mi][ni], 0, 0, 0);
  }
#pragma unroll
  for (int mi = 0; mi < 2; mi++)
#pragma unroll
    for (int ni = 0; ni < 2; ni++) {
      int m = wm * 32 + mi * 16 + (lane >> 4) * 4;
      int n = g0 + wn * 32 + ni * 16 + (lane & 15);
#pragma unroll
      for (int r = 0; r < 4; r++)
        P.xww[(size_t)(tb0 + m + r) * G4 + n] = cacc[mi][ni][r];
    }
}

__global__ __launch_bounds__(512)
__attribute__((amdgpu_waves_per_eu(2, 2)))
void fused_kernel(Params P) {
  __shared__ Smem S;
  int bid = blockIdx.x;
  if (bid < 64)        role_rec<0>(S.r, P.L, P, bid);
  else if (bid < 128)  role_rec<1>(S.r, P.L - 2, P, bid - 64);
  else                 role_gemm(S.g, P.L - 1, P);
}

// ---------------------------------------------------------------------------
__global__ void prep_kernel(const float* Wih0, const float* Whh0,
                            const float* bih0, const float* bhh0,
                            const float* Wih1, const float* Whh1,
                            const float* bih1, const float* bhh1,
                            const float* Whead, const float* bhead,
                            __half* wh0, __half* wh1, __half* wi1, __half* wi0,
                            __half* whd, float* bs0, float* bs1, float* bhd) {
  int i = blockIdx.x * blockDim.x + threadIdx.x;
  if (i < G4 * HID) {
    wh0[i] = __float2half(Whh0[i]);
    wh1[i] = __float2half(Whh1[i]);
    wi1[i] = __float2half(Wih1[i]);
  }
  if (i < G4 * INCH) wi0[i] = __float2half(Wih0[i]);
  if (i < OC * HID)  whd[i] = __float2half(Whead[i]);
  if (i < G4) { bs0[i] = bih0[i] + bhh0[i]; bs1[i] = bih1[i] + bhh1[i]; }
  if (i < OC) bhd[i] = bhead[i];
}

// ---------------------------------------------------------------------------
extern "C" void kernel_launch(void* const* d_in, const int* in_sizes, int n_in,
                              void* d_out, int out_size, void* d_ws, size_t ws_size,
                              hipStream_t stream) {
  const float* x     = (const float*)d_in[0];
  const float* Wih0  = (const float*)d_in[1];
  const float* Whh0  = (const float*)d_in[2];
  const float* bih0  = (const float*)d_in[3];
  const float* bhh0  = (const float*)d_in[4];
  const float* Wih1  = (const float*)d_in[5];
  const float* Whh1  = (const float*)d_in[6];
  const float* bih1  = (const float*)d_in[7];
  const float* bhh1  = (const float*)d_in[8];
  const float* Whead = (const float*)d_in[9];
  const float* bhead = (const float*)d_in[10];
  float* y = (float*)d_out;

  char* ws = (char*)d_ws;
  size_t cur = 0;
  auto alloc = [&](size_t sz) -> char* {
    char* p = ws + cur;
    cur = (cur + sz + 255) & ~(size_t)255;
    return p;
  };
  __half* wh0 = (__half*)alloc(G4 * HID * 2);
  __half* wh1 = (__half*)alloc(G4 * HID * 2);
  __half* wi1 = (__half*)alloc(G4 * HID * 2);
  __half* wi0 = (__half*)alloc(G4 * INCH * 2);
  __half* whd = (__half*)alloc(OC * HID * 2);
  float* bs0 = (float*)alloc(G4 * 4);
  float* bs1 = (float*)alloc(G4 * 4);
  float* bhd = (float*)alloc(OC * 4);
  float* h0s = (float*)alloc(NB * HID * 4);
  float* c0s = (float*)alloc(NB * HID * 4);
  float* h1s = (float*)alloc(NB * HID * 4);
  float* c1s = (float*)alloc(NB * HID * 4);
  size_t fixed = cur;

  int Tc = 512;
  while (Tc > 64) {
    size_t need = fixed + 2 * ((size_t)Tc * NB * HID * 2 + 512) +
                  2 * ((size_t)Tc * NB * G4 * 4 + 512);
    if (need <= ws_size) break;
    Tc >>= 1;
  }
  __half* h1buf[2];
  float* xwbuf[2];
  h1buf[0] = (__half*)alloc((size_t)Tc * NB * HID * 2);
  h1buf[1] = (__half*)alloc((size_t)Tc * NB * HID * 2);
  xwbuf[0] = (float*)alloc((size_t)Tc * NB * G4 * 4);
  xwbuf[1] = (float*)alloc((size_t)Tc * NB * G4 * 4);

  const int nch = T_SEQ / Tc;

  prep_kernel<<<(G4 * HID + 255) / 256, 256, 0, stream>>>(
      Wih0, Whh0, bih0, bhh0, Wih1, Whh1, bih1, bhh1, Whead, bhead,
      wh0, wh1, wi1, wi0, whd, bs0, bs1, bhd);

  const int ngemm = Tc * 8;
  for (int L = 0; L < nch + 2; ++L) {
    Params P;
    P.x = x;
    P.wh0 = wh0; P.wh1 = wh1; P.wi0 = wi0; P.wi1 = wi1; P.whd = whd;
    P.bs0 = bs0; P.bs1 = bs1; P.bhd = bhd;
    P.h0s = h0s; P.c0s = c0s; P.h1s = h1s; P.c1s = c1s;
    P.h1w = h1buf[L & 1];
    P.h1r = h1buf[(L + 1) & 1];
    P.xww = xwbuf[(L + 1) & 1];
    P.xwr = xwbuf[L & 1];
    P.y = y;
    P.L = L; P.Tc = Tc; P.nch = nch;
    fused_kernel<<<128 + ngemm, 512, 0, stream>>>(P);
  }
}